// Round 6
// baseline (560.558 us; speedup 1.0000x reference)
//
#include <hip/hip_runtime.h>
#include <math.h>
#include <stdint.h>

#define N 4096
#define S0 256
#define S1 128
#define S2 64
#define LDK 72    // k_sim LDS row stride in bf16 (144 B): conflict-free b128 reads
#define LDG 40    // k_loss1G LDS row stride in bf16 (80 B, 16B-aligned, 2-way free)

typedef __bf16 bf16;
typedef __attribute__((ext_vector_type(8))) __bf16 bf16x8;
typedef __attribute__((ext_vector_type(4))) __bf16 bf16x4;
typedef __attribute__((ext_vector_type(4))) float f32x4;
typedef unsigned long long u64;

// ---------------- k_prep: chain1 + chain2 + V2->bf16 + zero accumulators ----------------
// blocks [0,512): rows i0=bid*8 -> W fp32 (chain1) and hnb (chain2)
// blocks [512,576): V2b = bf16(V2), straight copy
// block 576: zero rowsum/pos2/pos3/pos4 + 4 lacc doubles

__global__ __launch_bounds__(128) void k_prep(const float* __restrict__ U0,
                                              const float* __restrict__ U1,
                                              const float* __restrict__ U2,
                                              const float* __restrict__ V2,
                                              const float* __restrict__ fc1_w,
                                              const float* __restrict__ fc1_b,
                                              const float* __restrict__ fc2_w,
                                              const float* __restrict__ fc2_b,
                                              float* __restrict__ W,
                                              bf16* __restrict__ V2b,
                                              bf16* __restrict__ hnb,
                                              float* __restrict__ accz) {
    __shared__ __align__(16) char pb[20480];
    int bid = blockIdx.x;
    int tid = threadIdx.x;

    if (bid < 512) {
        float (*u0s)[S0]      = (float(*)[S0])pb;                    // 8 KB
        float (*ts)[S1 + 4]   = (float(*)[S1 + 4])(pb + 8192);       // 4224
        float (*vs)[S2]       = (float(*)[S2])(pb + 12416);          // 2048
        float (*hs)[S1 + 4]   = (float(*)[S1 + 4])(pb + 14464);      // 4224
        float (*red)[8]       = (float(*)[8])(pb + 18688);           // 64
        float *norms          = (float*)(pb + 18752);                // 32
        int i0 = bid * 8;

        // ---- chain1: W = (U0@U1)@U2 fp32 ----
        for (int t = tid; t < 8 * S0; t += 128)
            u0s[t >> 8][t & 255] = U0[(i0 + (t >> 8)) * S0 + (t & 255)];
        __syncthreads();
        {
            int j = tid;
            float acc[8] = {};
            for (int k = 0; k < S0; ++k) {
                float u1 = U1[k * S1 + j];
#pragma unroll
                for (int r = 0; r < 8; ++r) acc[r] += u0s[r][k] * u1;
            }
            for (int r = 0; r < 8; ++r) ts[r][j] = acc[r];
        }
        __syncthreads();
        {
            int j = tid & 63, h = tid >> 6;
            float acc2[4] = {};
            for (int k = 0; k < S1; ++k) {
                float u2 = U2[k * S2 + j];
#pragma unroll
                for (int r = 0; r < 4; ++r) acc2[r] += ts[h * 4 + r][k] * u2;
            }
            for (int r = 0; r < 4; ++r)
                W[(i0 + h * 4 + r) * S2 + j] = acc2[r];
        }

        // ---- chain2: hnb = l2norm(elu(V2^T@fc1^T+b1)@fc2^T+b2) ----
        for (int t = tid; t < 8 * S2; t += 128) {
            int r = t & 7, k = t >> 3;
            vs[r][k] = V2[k * N + i0 + r];
        }
        __syncthreads();
        {
            int j = tid;
            float b = fc1_b[j];
            float acc[8];
#pragma unroll
            for (int r = 0; r < 8; ++r) acc[r] = b;
            for (int k = 0; k < S2; ++k) {
                float w = fc1_w[j * S2 + k];
#pragma unroll
                for (int r = 0; r < 8; ++r) acc[r] += vs[r][k] * w;
            }
            for (int r = 0; r < 8; ++r) {
                float x = acc[r];
                hs[r][j] = x > 0.f ? x : (expf(x) - 1.f);
            }
        }
        __syncthreads();
        {
            int j = tid;
            float b0 = fc2_b[j], b1 = fc2_b[j + 128];
            float a0[8], a1[8];
#pragma unroll
            for (int r = 0; r < 8; ++r) { a0[r] = b0; a1[r] = b1; }
            for (int k = 0; k < S1; ++k) {
                float w0 = fc2_w[j * S1 + k];
                float w1 = fc2_w[(j + 128) * S1 + k];
#pragma unroll
                for (int r = 0; r < 8; ++r) { a0[r] += hs[r][k] * w0; a1[r] += hs[r][k] * w1; }
            }
            int lane = tid & 63, wv = tid >> 6;
#pragma unroll
            for (int r = 0; r < 8; ++r) {
                float v = a0[r] * a0[r] + a1[r] * a1[r];
                for (int off = 32; off; off >>= 1) v += __shfl_down(v, off, 64);
                if (lane == 0) red[wv][r] = v;
            }
            __syncthreads();
            if (tid < 8) norms[tid] = fmaxf(sqrtf(red[0][tid] + red[1][tid]), 1e-12f);
            __syncthreads();
            for (int r = 0; r < 8; ++r) {
                float inv = 1.f / norms[r];
                hnb[(i0 + r) * S0 + j] = (bf16)(a0[r] * inv);
                hnb[(i0 + r) * S0 + j + 128] = (bf16)(a1[r] * inv);
            }
        }
    } else if (bid < 576) {
        // V2b = bf16(V2), element-order copy. 262144 elems = 65536 float4.
        int nb = bid - 512;
#pragma unroll
        for (int it = 0; it < 8; ++it) {
            int fi = nb * 1024 + it * 128 + tid;
            float4 x = *(const float4*)(V2 + (size_t)fi * 4);
            bf16x4 v = {(bf16)x.x, (bf16)x.y, (bf16)x.z, (bf16)x.w};
            *(bf16x4*)(V2b + (size_t)fi * 4) = v;
        }
    } else {
        // zero rowsum/pos2/pos3/pos4 (4N floats) + lacc (4 doubles = 8 floats)
        for (int t = tid; t < 4 * N + 8; t += 128) accz[t] = 0.f;
    }
}

// ---------------- k_mask: sim>0.9 ballot bitmask (permuted layout) + loss5 ----------------
// Layout: word[row*64 + stripe*4 + u], bit l = (sim[row, stripe*256 + l*4 + u] > 0.9)
// blocks [0,1024): mask (1 wave per row); blocks [1024,1064): loss5

__global__ __launch_bounds__(256) void k_mask(const float* __restrict__ sim,
                                              u64* __restrict__ mask,
                                              const float* __restrict__ U0,
                                              const float* __restrict__ U1,
                                              const float* __restrict__ U2,
                                              const float* __restrict__ V2,
                                              double* __restrict__ acc5) {
    int bid = blockIdx.x;
    int tid = threadIdx.x;
    if (bid < 1024) {
        int lane = tid & 63;
        int row = bid * 4 + (tid >> 6);          // one wave per row
        const float* base = sim + (size_t)row * N + lane * 4;
#pragma unroll
        for (int half = 0; half < 2; ++half) {
            float4 x[8];
#pragma unroll
            for (int it = 0; it < 8; ++it)
                x[it] = *(const float4*)(base + (half * 8 + it) * 256);
#pragma unroll
            for (int it = 0; it < 8; ++it) {
                u64 b0 = __ballot(x[it].x > 0.9f);
                u64 b1 = __ballot(x[it].y > 0.9f);
                u64 b2 = __ballot(x[it].z > 0.9f);
                u64 b3 = __ballot(x[it].w > 0.9f);
                if (lane < 4) {
                    u64 v = (lane == 0) ? b0 : (lane == 1) ? b1 : (lane == 2) ? b2 : b3;
                    mask[(size_t)row * 64 + (half * 8 + it) * 4 + lane] = v;
                }
            }
        }
    } else {
        const int n0 = N * S0, n1 = S0 * S1, n2 = S1 * S2, n3 = S2 * N;
        const int total = n0 + n1 + n2 + n3;
        float local = 0.f;
        for (int t = (bid - 1024) * 256 + tid; t < total; t += 40 * 256) {
            int u = t;
            float x;
            if (u < n0) x = U0[u];
            else { u -= n0;
                if (u < n1) x = U1[u];
                else { u -= n1;
                    if (u < n2) x = U2[u];
                    else { u -= n2; x = V2[u]; }
                }
            }
            if (x < 0.f) local += x * x;
        }
        for (int off = 32; off; off >>= 1) local += __shfl_down(local, off, 64);
        if ((tid & 63) == 0 && local != 0.f) atomicAdd(acc5, (double)local);
    }
}

// ------- k_loss1G: G = A @ V2^T (N x 64, K=4096) + fused sum(A^2) -------
// grid 256: split = bid>>5 (K range of 512), rb = bid&31 (128-row block)

__global__ __launch_bounds__(256) void k_loss1G(const float* __restrict__ A,
                                                const bf16* __restrict__ V2b,
                                                float* __restrict__ Gp,
                                                double* __restrict__ lacc) {
    __shared__ __align__(16) bf16 As[128 * LDG];
    __shared__ __align__(16) bf16 Bs[64 * LDG];
    __shared__ float reds[4];
    int tid = threadIdx.x, lane = tid & 63, w = tid >> 6;
    int split = blockIdx.x >> 5, rb = blockIdx.x & 31;
    int i0 = rb * 128, k0 = split * 512;
    int q = lane >> 4, l15 = lane & 15;

    f32x4 zero = {0.f, 0.f, 0.f, 0.f};
    f32x4 acc[2][4];
#pragma unroll
    for (int a = 0; a < 2; ++a)
#pragma unroll
        for (int b = 0; b < 4; ++b) acc[a][b] = zero;
    float a2 = 0.f;

    for (int ch = 0; ch < 16; ++ch) {
        int jb = k0 + ch * 32;
        __syncthreads();
#pragma unroll
        for (int t = 0; t < 4; ++t) {
            int fi = tid + 256 * t;
            int row = fi >> 3, c4 = fi & 7;
            float4 x = *(const float4*)(A + (size_t)(i0 + row) * N + jb + c4 * 4);
            a2 += x.x * x.x + x.y * x.y + x.z * x.z + x.w * x.w;
            bf16x4 v = {(bf16)x.x, (bf16)x.y, (bf16)x.z, (bf16)x.w};
            *(bf16x4*)(As + row * LDG + c4 * 4) = v;
        }
        {
            // FIX(R5->R6): all 256 threads stage 64 rows x 32 cols (was 16 cols)
            int row = tid >> 2, c8 = tid & 3;
            uint4 v = *(const uint4*)(V2b + (size_t)row * N + jb + c8 * 8);
            *(uint4*)(Bs + row * LDG + c8 * 8) = v;
        }
        __syncthreads();
        bf16x8 af[2], bfr[4];
#pragma unroll
        for (int ta = 0; ta < 2; ++ta)
            af[ta] = *(const bf16x8*)(As + (w * 32 + ta * 16 + l15) * LDG + q * 8);
#pragma unroll
        for (int tb = 0; tb < 4; ++tb)
            bfr[tb] = *(const bf16x8*)(Bs + (tb * 16 + l15) * LDG + q * 8);
#pragma unroll
        for (int ta = 0; ta < 2; ++ta)
#pragma unroll
            for (int tb = 0; tb < 4; ++tb)
                acc[ta][tb] = __builtin_amdgcn_mfma_f32_16x16x32_bf16(af[ta], bfr[tb], acc[ta][tb], 0, 0, 0);
    }
    // write G partial for this K-split
    float* G = Gp + (size_t)split * (N * S2);
#pragma unroll
    for (int ta = 0; ta < 2; ++ta)
#pragma unroll
        for (int v = 0; v < 4; ++v) {
            int i = i0 + w * 32 + ta * 16 + q * 4 + v;
#pragma unroll
            for (int tb = 0; tb < 4; ++tb)
                G[(size_t)i * S2 + tb * 16 + l15] = acc[ta][tb][v];
        }
    // reduce sum(A^2)
    for (int off = 32; off; off >>= 1) a2 += __shfl_down(a2, off, 64);
    if (lane == 0) reds[w] = a2;
    __syncthreads();
    if (tid == 0) atomicAdd(lacc + 0, (double)(reds[0] + reds[1] + reds[2] + reds[3]));
}

// ------- k_fin1: sumP2 = sum (W^T W) o (V2 V2^T), cross = sum W o G -------
// blocks [0,128): 32 (k,l) pairs each; blocks [128,160): cross-term

__global__ __launch_bounds__(256) void k_fin1(const float* __restrict__ W,
                                              const float* __restrict__ V2,
                                              const float* __restrict__ Gp,
                                              double* __restrict__ lacc) {
    __shared__ float r1[4], r2[4];
    int bid = blockIdx.x, tid = threadIdx.x, lane = tid & 63, w = tid >> 6;
    if (bid < 128) {
        double bacc = 0.0;
        for (int pi = 0; pi < 32; ++pi) {
            int p = bid * 32 + pi;
            int k = p >> 6, l = p & 63;
            float s1 = 0.f, s2 = 0.f;
            for (int i = tid; i < N; i += 256)
                s1 += W[i * S2 + k] * W[i * S2 + l];
            for (int j = tid; j < N; j += 256)
                s2 += V2[(size_t)k * N + j] * V2[(size_t)l * N + j];
            for (int off = 32; off; off >>= 1) {
                s1 += __shfl_down(s1, off, 64);
                s2 += __shfl_down(s2, off, 64);
            }
            if (lane == 0) { r1[w] = s1; r2[w] = s2; }
            __syncthreads();
            if (tid == 0)
                bacc += (double)(r1[0] + r1[1] + r1[2] + r1[3]) *
                        (double)(r2[0] + r2[1] + r2[2] + r2[3]);
            __syncthreads();
        }
        if (tid == 0) atomicAdd(lacc + 3, bacc);
    } else {
        int b = bid - 128;           // 32 blocks over 262144 elements
        float c = 0.f;
        for (int e = b * 8192 + tid; e < (b + 1) * 8192; e += 256) {
            float g = 0.f;
#pragma unroll
            for (int s = 0; s < 8; ++s) g += Gp[(size_t)s * (N * S2) + e];
            c += W[e] * g;
        }
        for (int off = 32; off; off >>= 1) c += __shfl_down(c, off, 64);
        __shared__ float rc[4];
        if (lane == 0) rc[w] = c;
        __syncthreads();
        if (tid == 0) atomicAdd(lacc + 2, (double)(rc[0] + rc[1] + rc[2] + rc[3]));
    }
}

// ------- k_sim fused: refl_sim rowsum + bitmask pos + pos_idx tail blocks -------

__global__ __launch_bounds__(256) void k_sim(const bf16* __restrict__ hnb,
                                             const u64* __restrict__ mask,
                                             float* __restrict__ rowsum,
                                             float* __restrict__ pos4,
                                             const int* __restrict__ cIdx,
                                             const int* __restrict__ nIdx,
                                             float* __restrict__ pos2,
                                             float* __restrict__ pos3) {
    int bid = blockIdx.x;
    int tid = threadIdx.x;
    if (bid >= 1024) {
        // ---- pos_idx path ----
        int g = (bid - 1024) * 256 + tid;
        if (g >= N * 24) return;
        int i = g / 24, s = g % 24;
        const int* idx;
        int kk;
        float* dst;
        if (s < 8) { idx = cIdx + i * 8; kk = s; dst = pos2; }
        else       { idx = nIdx + i * 16; kk = s - 8; dst = pos3; }
        int t = idx[kk];
        for (int k = 0; k < kk; ++k)
            if (idx[k] == t) return;  // mask is a set: duplicates count once
        const bf16* a = hnb + i * S0;
        const bf16* b = hnb + t * S0;
        float dsum = 0.f;
        for (int k = 0; k < S0; k += 8) {
            bf16x8 av = *(const bf16x8*)(a + k);
            bf16x8 bv = *(const bf16x8*)(b + k);
#pragma unroll
            for (int u = 0; u < 8; ++u) dsum += (float)av[u] * (float)bv[u];
        }
        atomicAdd(dst + i, __expf(2.f * dsum));
        return;
    }

    __shared__ __align__(16) bf16 As[128 * LDK];
    __shared__ __align__(16) bf16 Bs[128 * LDK];
    __shared__ float rs_l[128], ps_l[128];
    int lane = tid & 63, w = tid >> 6;
    int i0 = (bid >> 5) * 128, j0 = (bid & 31) * 128;
    int wm = (w >> 1) * 64, wn = (w & 1) * 64;
    if (tid < 128) { rs_l[tid] = 0.f; ps_l[tid] = 0.f; }

    f32x4 zero = {0.f, 0.f, 0.f, 0.f};
    f32x4 d[4][4];
#pragma unroll
    for (int a = 0; a < 4; ++a)
#pragma unroll
        for (int b = 0; b < 4; ++b) d[a][b] = zero;

    int q = lane >> 4, l15 = lane & 15;
    for (int k0 = 0; k0 < S0; k0 += 64) {
        __syncthreads();
#pragma unroll
        for (int t = 0; t < 4; ++t) {
            int idx = tid + 256 * t;
            int r = idx >> 3, c = idx & 7;
            uint4 va = *(const uint4*)(hnb + (i0 + r) * S0 + k0 + c * 8);
            uint4 vb = *(const uint4*)(hnb + (j0 + r) * S0 + k0 + c * 8);
            *(uint4*)(As + r * LDK + c * 8) = va;
            *(uint4*)(Bs + r * LDK + c * 8) = vb;
        }
        __syncthreads();
#pragma unroll
        for (int kk = 0; kk < 64; kk += 32) {
            bf16x8 af[4], bfr[4];
#pragma unroll
            for (int ta = 0; ta < 4; ++ta)
                af[ta] = *(const bf16x8*)(As + (wm + ta * 16 + l15) * LDK + kk + q * 8);
#pragma unroll
            for (int tb = 0; tb < 4; ++tb)
                bfr[tb] = *(const bf16x8*)(Bs + (wn + tb * 16 + l15) * LDK + kk + q * 8);
#pragma unroll
            for (int ta = 0; ta < 4; ++ta)
#pragma unroll
                for (int tb = 0; tb < 4; ++tb)
                    d[ta][tb] = __builtin_amdgcn_mfma_f32_16x16x32_bf16(af[ta], bfr[tb], d[ta][tb], 0, 0, 0);
        }
    }
    // stage this block's mask words into reused LDS (512 x u64 = 4 KB)
    __syncthreads();
    u64* mwords = (u64*)As;
    int stripe = j0 >> 8, half = (j0 >> 7) & 1;
    for (int t = tid; t < 512; t += 256) {
        int li = t >> 2, u = t & 3;
        mwords[t] = mask[(size_t)(i0 + li) * 64 + stripe * 4 + u];
    }
    __syncthreads();
    // epilogue: s = exp(2*dot); permuted-layout mask bit
    int bitbase = half * 32 + (wn >> 2) + (l15 >> 2);
    int uoff = l15 & 3;
#pragma unroll
    for (int ta = 0; ta < 4; ++ta)
#pragma unroll
        for (int v = 0; v < 4; ++v) {
            int li = wm + ta * 16 + q * 4 + v;
            u64 word = mwords[li * 4 + uoff];
            float rs = 0.f, ps = 0.f;
#pragma unroll
            for (int tb = 0; tb < 4; ++tb) {
                float s = __expf(2.f * d[ta][tb][v]);
                rs += s;
                ps += ((word >> (bitbase + tb * 4)) & 1ULL) ? s : 0.f;
            }
#pragma unroll
            for (int m = 1; m < 16; m <<= 1) {
                rs += __shfl_xor(rs, m, 16);
                ps += __shfl_xor(ps, m, 16);
            }
            if (l15 == 0) {
                atomicAdd(&rs_l[li], rs);
                atomicAdd(&ps_l[li], ps);
            }
        }
    __syncthreads();
    if (tid < 128) {
        atomicAdd(&rowsum[i0 + tid], rs_l[tid]);
        atomicAdd(&pos4[i0 + tid], ps_l[tid]);
    }
}

// ---------------- finalize ----------------

__global__ __launch_bounds__(256) void k_final(const float* __restrict__ rowsum,
                                               const float* __restrict__ pos2,
                                               const float* __restrict__ pos3,
                                               const float* __restrict__ pos4,
                                               const double* __restrict__ lacc,
                                               float* __restrict__ out) {
    __shared__ double red[3][4];
    int tid = threadIdx.x;
    double l2 = 0, l3 = 0, l4 = 0;
    for (int i = tid; i < N; i += 256) {
        double rs = (double)rowsum[i];
        float p2 = pos2[i], p3 = pos3[i], p4 = pos4[i];
        if (p2 > 0.f) l2 -= log((double)p2 / rs);
        if (p3 > 0.f) l3 -= log((double)p3 / rs);
        if (p4 > 0.f) l4 -= log((double)p4 / rs);
    }
    int lane = tid & 63, wave = tid >> 6;
    for (int off = 32; off; off >>= 1) {
        l2 += __shfl_down(l2, off, 64);
        l3 += __shfl_down(l3, off, 64);
        l4 += __shfl_down(l4, off, 64);
    }
    if (lane == 0) { red[0][wave] = l2; red[1][wave] = l3; red[2][wave] = l4; }
    __syncthreads();
    if (tid == 0) {
        double L2 = 0, L3 = 0, L4 = 0;
        for (int w = 0; w < 4; ++w) { L2 += red[0][w]; L3 += red[1][w]; L4 += red[2][w]; }
        L2 /= N; L3 /= N; L4 /= N;
        double L1 = lacc[0] - 2.0 * lacc[2] + lacc[3];   // sumA2 - 2*cross + sumP2
        double L5 = lacc[1];
        double total = L1 + 0.1 * (L2 + L3 + L4) + L5;
        out[0] = (float)total;
        out[1] = (float)L1;
        out[2] = (float)L2;
        out[3] = (float)L3;
        out[4] = (float)L4;
        out[5] = (float)L5;
    }
}

extern "C" void kernel_launch(void* const* d_in, const int* in_sizes, int n_in,
                              void* d_out, int out_size, void* d_ws, size_t ws_size,
                              hipStream_t stream) {
    const float* A     = (const float*)d_in[0];
    const float* U0    = (const float*)d_in[1];
    const float* U1    = (const float*)d_in[2];
    const float* U2    = (const float*)d_in[3];
    const float* V2    = (const float*)d_in[4];
    const float* fc1_w = (const float*)d_in[5];
    const float* fc1_b = (const float*)d_in[6];
    const float* fc2_w = (const float*)d_in[7];
    const float* fc2_b = (const float*)d_in[8];
    const float* sim   = (const float*)d_in[9];
    const int* cIdx    = (const int*)d_in[10];
    const int* nIdx    = (const int*)d_in[11];

    float* ws = (float*)d_ws;
    float* rowsum = ws;
    float* pos2 = ws + N;
    float* pos3 = ws + 2 * N;
    float* pos4 = ws + 3 * N;
    double* lacc = (double*)(ws + 4 * N);            // 4 doubles: sumA2, loss5, cross, sumP2
    u64* mask = (u64*)(ws + 4 * N + 8);              // N*64 words = 2 MB (16B-aligned)
    bf16* hnb = (bf16*)(mask + (size_t)N * 64);      // N*S0 bf16 = 2 MB
    float* W  = (float*)(hnb + (size_t)N * S0);      // N*S2 fp32 = 1 MB
    bf16* V2b = (bf16*)(W + (size_t)N * S2);         // S2*N bf16 = 0.5 MB
    float* Gp = (float*)(V2b + (size_t)S2 * N);      // 8 * N*S2 fp32 = 8 MB

    k_prep<<<577, 128, 0, stream>>>(U0, U1, U2, V2, fc1_w, fc1_b, fc2_w, fc2_b,
                                    W, V2b, hnb, ws);
    k_mask<<<1064, 256, 0, stream>>>(sim, mask, U0, U1, U2, V2, lacc + 1);
    k_loss1G<<<256, 256, 0, stream>>>(A, V2b, Gp, lacc);
    k_fin1<<<160, 256, 0, stream>>>(W, V2, Gp, lacc);
    k_sim<<<1024 + 384, 256, 0, stream>>>(hnb, mask, rowsum, pos4,
                                          cIdx, nIdx, pos2, pos3);
    k_final<<<1, 256, 0, stream>>>(rowsum, pos2, pos3, pos4, lacc, (float*)d_out);
}

// Round 7
// 317.948 us; speedup vs baseline: 1.7630x; 1.7630x over previous
//
#include <hip/hip_runtime.h>
#include <math.h>
#include <stdint.h>

#define N 4096
#define S0 256
#define S1 128
#define S2 64
#define LDK 72    // k_sim LDS row stride in bf16 (144 B): conflict-free b128 reads
#define LDG 40    // k_loss1G LDS row stride in bf16 (80 B, 16B-aligned)

typedef __bf16 bf16;
typedef __attribute__((ext_vector_type(8))) __bf16 bf16x8;
typedef __attribute__((ext_vector_type(4))) __bf16 bf16x4;
typedef __attribute__((ext_vector_type(4))) float f32x4;
typedef unsigned long long u64;

// ---------------- k_prep: chain1(+Wt) + chain2 + V2->bf16 + zero accumulators ----------------
// blocks [0,512): rows i0=bid*8 -> W/Wt fp32 (chain1) and hnb (chain2)
// blocks [512,576): V2b = bf16(V2)
// block 576: zero rowsum/pos2/pos3/pos4 + 4 lacc doubles

__global__ __launch_bounds__(128) void k_prep(const float* __restrict__ U0,
                                              const float* __restrict__ U1,
                                              const float* __restrict__ U2,
                                              const float* __restrict__ V2,
                                              const float* __restrict__ fc1_w,
                                              const float* __restrict__ fc1_b,
                                              const float* __restrict__ fc2_w,
                                              const float* __restrict__ fc2_b,
                                              float* __restrict__ W,
                                              float* __restrict__ Wt,
                                              bf16* __restrict__ V2b,
                                              bf16* __restrict__ hnb,
                                              float* __restrict__ accz) {
    __shared__ __align__(16) char pb[20480];
    int bid = blockIdx.x;
    int tid = threadIdx.x;

    if (bid < 512) {
        float (*u0s)[S0]      = (float(*)[S0])pb;                    // 8 KB
        float (*ts)[S1 + 4]   = (float(*)[S1 + 4])(pb + 8192);       // 4224
        float (*vs)[S2]       = (float(*)[S2])(pb + 12416);          // 2048
        float (*hs)[S1 + 4]   = (float(*)[S1 + 4])(pb + 14464);      // 4224
        float (*red)[8]       = (float(*)[8])(pb + 18688);           // 64
        float *norms          = (float*)(pb + 18752);                // 32
        int i0 = bid * 8;

        // ---- chain1: W = (U0@U1)@U2 fp32, plus transposed copy Wt ----
        for (int t = tid; t < 8 * S0; t += 128)
            u0s[t >> 8][t & 255] = U0[(i0 + (t >> 8)) * S0 + (t & 255)];
        __syncthreads();
        {
            int j = tid;
            float acc[8] = {};
            for (int k = 0; k < S0; ++k) {
                float u1 = U1[k * S1 + j];
#pragma unroll
                for (int r = 0; r < 8; ++r) acc[r] += u0s[r][k] * u1;
            }
            for (int r = 0; r < 8; ++r) ts[r][j] = acc[r];
        }
        __syncthreads();
        {
            int j = tid & 63, h = tid >> 6;
            float acc2[4] = {};
            for (int k = 0; k < S1; ++k) {
                float u2 = U2[k * S2 + j];
#pragma unroll
                for (int r = 0; r < 4; ++r) acc2[r] += ts[h * 4 + r][k] * u2;
            }
            for (int r = 0; r < 4; ++r) {
                int i = i0 + h * 4 + r;
                W[i * S2 + j] = acc2[r];
                Wt[(size_t)j * N + i] = acc2[r];
            }
        }

        // ---- chain2: hnb = l2norm(elu(V2^T@fc1^T+b1)@fc2^T+b2) ----
        for (int t = tid; t < 8 * S2; t += 128) {
            int r = t & 7, k = t >> 3;
            vs[r][k] = V2[k * N + i0 + r];
        }
        __syncthreads();
        {
            int j = tid;
            float b = fc1_b[j];
            float acc[8];
#pragma unroll
            for (int r = 0; r < 8; ++r) acc[r] = b;
            for (int k = 0; k < S2; ++k) {
                float w = fc1_w[j * S2 + k];
#pragma unroll
                for (int r = 0; r < 8; ++r) acc[r] += vs[r][k] * w;
            }
            for (int r = 0; r < 8; ++r) {
                float x = acc[r];
                hs[r][j] = x > 0.f ? x : (expf(x) - 1.f);
            }
        }
        __syncthreads();
        {
            int j = tid;
            float b0 = fc2_b[j], b1 = fc2_b[j + 128];
            float a0[8], a1[8];
#pragma unroll
            for (int r = 0; r < 8; ++r) { a0[r] = b0; a1[r] = b1; }
            for (int k = 0; k < S1; ++k) {
                float w0 = fc2_w[j * S1 + k];
                float w1 = fc2_w[(j + 128) * S1 + k];
#pragma unroll
                for (int r = 0; r < 8; ++r) { a0[r] += hs[r][k] * w0; a1[r] += hs[r][k] * w1; }
            }
            int lane = tid & 63, wv = tid >> 6;
#pragma unroll
            for (int r = 0; r < 8; ++r) {
                float v = a0[r] * a0[r] + a1[r] * a1[r];
                for (int off = 32; off; off >>= 1) v += __shfl_down(v, off, 64);
                if (lane == 0) red[wv][r] = v;
            }
            __syncthreads();
            if (tid < 8) norms[tid] = fmaxf(sqrtf(red[0][tid] + red[1][tid]), 1e-12f);
            __syncthreads();
            for (int r = 0; r < 8; ++r) {
                float inv = 1.f / norms[r];
                hnb[(i0 + r) * S0 + j] = (bf16)(a0[r] * inv);
                hnb[(i0 + r) * S0 + j + 128] = (bf16)(a1[r] * inv);
            }
        }
    } else if (bid < 576) {
        int nb = bid - 512;
#pragma unroll
        for (int it = 0; it < 8; ++it) {
            int fi = nb * 1024 + it * 128 + tid;
            float4 x = *(const float4*)(V2 + (size_t)fi * 4);
            bf16x4 v = {(bf16)x.x, (bf16)x.y, (bf16)x.z, (bf16)x.w};
            *(bf16x4*)(V2b + (size_t)fi * 4) = v;
        }
    } else {
        for (int t = tid; t < 4 * N + 8; t += 128) accz[t] = 0.f;
    }
}

// ---------------- k_mid: mask + loss5 + loss1G(cross+sumA2) + gram pairs ----------------
// blocks [0,1024): sim bitmask (permuted layout, 1 wave/row)
// blocks [1024,1064): loss5
// blocks [1064,1320): G=A@V2^T MFMA; epilogue: cross=sum W o G, sum(A^2)
// blocks [1320,2344): gram pairs: pairsum[b] = sum_w (Wt[k].Wt[l]) * (V2[k].V2[l])

__global__ __launch_bounds__(256) void k_mid(const float* __restrict__ sim,
                                             u64* __restrict__ mask,
                                             const float* __restrict__ U0,
                                             const float* __restrict__ U1,
                                             const float* __restrict__ U2,
                                             const float* __restrict__ V2,
                                             const float* __restrict__ A,
                                             const bf16* __restrict__ V2b,
                                             const float* __restrict__ W,
                                             const float* __restrict__ Wt,
                                             double* __restrict__ lacc,
                                             double* __restrict__ pairsum) {
    __shared__ __align__(16) char smem[15488];
    int bid = blockIdx.x;
    int tid = threadIdx.x;
    int lane = tid & 63, w = tid >> 6;

    if (bid < 1024) {
        // ---- sim>0.9 ballot bitmask ----
        int row = bid * 4 + w;
        const float* base = sim + (size_t)row * N + lane * 4;
#pragma unroll
        for (int half = 0; half < 2; ++half) {
            float4 x[8];
#pragma unroll
            for (int it = 0; it < 8; ++it)
                x[it] = *(const float4*)(base + (half * 8 + it) * 256);
#pragma unroll
            for (int it = 0; it < 8; ++it) {
                u64 b0 = __ballot(x[it].x > 0.9f);
                u64 b1 = __ballot(x[it].y > 0.9f);
                u64 b2 = __ballot(x[it].z > 0.9f);
                u64 b3 = __ballot(x[it].w > 0.9f);
                if (lane < 4) {
                    u64 v = (lane == 0) ? b0 : (lane == 1) ? b1 : (lane == 2) ? b2 : b3;
                    mask[(size_t)row * 64 + (half * 8 + it) * 4 + lane] = v;
                }
            }
        }
    } else if (bid < 1064) {
        // ---- loss5 ----
        const int n0 = N * S0, n1 = S0 * S1, n2 = S1 * S2, n3 = S2 * N;
        const int total = n0 + n1 + n2 + n3;
        float local = 0.f;
        for (int t = (bid - 1024) * 256 + tid; t < total; t += 40 * 256) {
            int u = t;
            float x;
            if (u < n0) x = U0[u];
            else { u -= n0;
                if (u < n1) x = U1[u];
                else { u -= n1;
                    if (u < n2) x = U2[u];
                    else { u -= n2; x = V2[u]; }
                }
            }
            if (x < 0.f) local += x * x;
        }
        for (int off = 32; off; off >>= 1) local += __shfl_down(local, off, 64);
        if (lane == 0 && local != 0.f) atomicAdd(lacc + 1, (double)local);
    } else if (bid < 1320) {
        // ---- loss1G: MFMA G-tile + fused cross & sumA2 ----
        bf16* As = (bf16*)smem;                      // 128*LDG*2 = 10240
        bf16* Bs = As + 128 * LDG;                   // 64*LDG*2  = 5120
        float* reds = (float*)(smem + 15360);        // 16
        float* redc = reds + 4;                      // 16
        int b = bid - 1064;
        int split = b >> 5, rb = b & 31;
        int i0 = rb * 128, k0 = split * 512;
        int q = lane >> 4, l15 = lane & 15;

        f32x4 zero = {0.f, 0.f, 0.f, 0.f};
        f32x4 acc[2][4];
#pragma unroll
        for (int a = 0; a < 2; ++a)
#pragma unroll
            for (int c = 0; c < 4; ++c) acc[a][c] = zero;
        float a2 = 0.f;

        for (int ch = 0; ch < 16; ++ch) {
            int jb = k0 + ch * 32;
            __syncthreads();
#pragma unroll
            for (int t = 0; t < 4; ++t) {
                int fi = tid + 256 * t;
                int row = fi >> 3, c4 = fi & 7;
                float4 x = *(const float4*)(A + (size_t)(i0 + row) * N + jb + c4 * 4);
                a2 += x.x * x.x + x.y * x.y + x.z * x.z + x.w * x.w;
                bf16x4 v = {(bf16)x.x, (bf16)x.y, (bf16)x.z, (bf16)x.w};
                *(bf16x4*)(As + row * LDG + c4 * 4) = v;
            }
            {
                int row = tid >> 2, c8 = tid & 3;
                uint4 v = *(const uint4*)(V2b + (size_t)row * N + jb + c8 * 8);
                *(uint4*)(Bs + row * LDG + c8 * 8) = v;
            }
            __syncthreads();
            bf16x8 af[2], bfr[4];
#pragma unroll
            for (int ta = 0; ta < 2; ++ta)
                af[ta] = *(const bf16x8*)(As + (w * 32 + ta * 16 + l15) * LDG + q * 8);
#pragma unroll
            for (int tb = 0; tb < 4; ++tb)
                bfr[tb] = *(const bf16x8*)(Bs + (tb * 16 + l15) * LDG + q * 8);
#pragma unroll
            for (int ta = 0; ta < 2; ++ta)
#pragma unroll
                for (int tb = 0; tb < 4; ++tb)
                    acc[ta][tb] = __builtin_amdgcn_mfma_f32_16x16x32_bf16(af[ta], bfr[tb], acc[ta][tb], 0, 0, 0);
        }
        // cross partial: sum W[i][col] * G[i][col]
        float cr = 0.f;
#pragma unroll
        for (int ta = 0; ta < 2; ++ta)
#pragma unroll
            for (int v = 0; v < 4; ++v) {
                int i = i0 + w * 32 + ta * 16 + q * 4 + v;
                const float* wrow = W + (size_t)i * S2 + l15;
#pragma unroll
                for (int tb = 0; tb < 4; ++tb)
                    cr += wrow[tb * 16] * acc[ta][tb][v];
            }
        for (int off = 32; off; off >>= 1) {
            cr += __shfl_down(cr, off, 64);
            a2 += __shfl_down(a2, off, 64);
        }
        if (lane == 0) { reds[w] = a2; redc[w] = cr; }
        __syncthreads();
        if (tid == 0) {
            atomicAdd(lacc + 0, (double)(reds[0] + reds[1] + reds[2] + reds[3]));
            atomicAdd(lacc + 2, (double)(redc[0] + redc[1] + redc[2] + redc[3]));
        }
    } else {
        // ---- gram pairs: one wave per (k,l) ----
        double* gred = (double*)smem;
        int p = (bid - 1320) * 4 + w;
        int kk = p >> 6, ll = p & 63;
        const float* wk = Wt + (size_t)kk * N;
        const float* wl = Wt + (size_t)ll * N;
        const float* vk = V2 + (size_t)kk * N;
        const float* vl = V2 + (size_t)ll * N;
        float s1 = 0.f, s2 = 0.f;
        for (int it = 0; it < 16; ++it) {
            int j = it * 256 + lane * 4;
            float4 a1 = *(const float4*)(wk + j);
            float4 b1 = *(const float4*)(wl + j);
            float4 a2v = *(const float4*)(vk + j);
            float4 b2v = *(const float4*)(vl + j);
            s1 += a1.x * b1.x + a1.y * b1.y + a1.z * b1.z + a1.w * b1.w;
            s2 += a2v.x * b2v.x + a2v.y * b2v.y + a2v.z * b2v.z + a2v.w * b2v.w;
        }
        for (int off = 32; off; off >>= 1) {
            s1 += __shfl_down(s1, off, 64);
            s2 += __shfl_down(s2, off, 64);
        }
        if (lane == 0) gred[w] = (double)s1 * (double)s2;
        __syncthreads();
        if (tid == 0)
            pairsum[bid - 1320] = gred[0] + gred[1] + gred[2] + gred[3];
    }
}

// ------- k_sim fused: refl_sim rowsum + bitmask pos + pos_idx tail blocks -------

__global__ __launch_bounds__(256) void k_sim(const bf16* __restrict__ hnb,
                                             const u64* __restrict__ mask,
                                             float* __restrict__ rowsum,
                                             float* __restrict__ pos4,
                                             const int* __restrict__ cIdx,
                                             const int* __restrict__ nIdx,
                                             float* __restrict__ pos2,
                                             float* __restrict__ pos3) {
    int bid = blockIdx.x;
    int tid = threadIdx.x;
    if (bid >= 1024) {
        int g = (bid - 1024) * 256 + tid;
        if (g >= N * 24) return;
        int i = g / 24, s = g % 24;
        const int* idx;
        int kk;
        float* dst;
        if (s < 8) { idx = cIdx + i * 8; kk = s; dst = pos2; }
        else       { idx = nIdx + i * 16; kk = s - 8; dst = pos3; }
        int t = idx[kk];
        for (int k = 0; k < kk; ++k)
            if (idx[k] == t) return;  // mask is a set: duplicates count once
        const bf16* a = hnb + i * S0;
        const bf16* b = hnb + t * S0;
        float dsum = 0.f;
        for (int k = 0; k < S0; k += 8) {
            bf16x8 av = *(const bf16x8*)(a + k);
            bf16x8 bv = *(const bf16x8*)(b + k);
#pragma unroll
            for (int u = 0; u < 8; ++u) dsum += (float)av[u] * (float)bv[u];
        }
        atomicAdd(dst + i, __expf(2.f * dsum));
        return;
    }

    __shared__ __align__(16) bf16 As[128 * LDK];
    __shared__ __align__(16) bf16 Bs[128 * LDK];
    __shared__ float rs_l[128], ps_l[128];
    int lane = tid & 63, w = tid >> 6;
    int i0 = (bid >> 5) * 128, j0 = (bid & 31) * 128;
    int wm = (w >> 1) * 64, wn = (w & 1) * 64;
    if (tid < 128) { rs_l[tid] = 0.f; ps_l[tid] = 0.f; }

    f32x4 zero = {0.f, 0.f, 0.f, 0.f};
    f32x4 d[4][4];
#pragma unroll
    for (int a = 0; a < 4; ++a)
#pragma unroll
        for (int b = 0; b < 4; ++b) d[a][b] = zero;

    int q = lane >> 4, l15 = lane & 15;
    for (int k0 = 0; k0 < S0; k0 += 64) {
        __syncthreads();
#pragma unroll
        for (int t = 0; t < 4; ++t) {
            int idx = tid + 256 * t;
            int r = idx >> 3, c = idx & 7;
            uint4 va = *(const uint4*)(hnb + (i0 + r) * S0 + k0 + c * 8);
            uint4 vb = *(const uint4*)(hnb + (j0 + r) * S0 + k0 + c * 8);
            *(uint4*)(As + r * LDK + c * 8) = va;
            *(uint4*)(Bs + r * LDK + c * 8) = vb;
        }
        __syncthreads();
#pragma unroll
        for (int kk = 0; kk < 64; kk += 32) {
            bf16x8 af[4], bfr[4];
#pragma unroll
            for (int ta = 0; ta < 4; ++ta)
                af[ta] = *(const bf16x8*)(As + (wm + ta * 16 + l15) * LDK + kk + q * 8);
#pragma unroll
            for (int tb = 0; tb < 4; ++tb)
                bfr[tb] = *(const bf16x8*)(Bs + (wn + tb * 16 + l15) * LDK + kk + q * 8);
#pragma unroll
            for (int ta = 0; ta < 4; ++ta)
#pragma unroll
                for (int tb = 0; tb < 4; ++tb)
                    d[ta][tb] = __builtin_amdgcn_mfma_f32_16x16x32_bf16(af[ta], bfr[tb], d[ta][tb], 0, 0, 0);
        }
    }
    __syncthreads();
    u64* mwords = (u64*)As;
    int stripe = j0 >> 8, half = (j0 >> 7) & 1;
    for (int t = tid; t < 512; t += 256) {
        int li = t >> 2, u = t & 3;
        mwords[t] = mask[(size_t)(i0 + li) * 64 + stripe * 4 + u];
    }
    __syncthreads();
    int bitbase = half * 32 + (wn >> 2) + (l15 >> 2);
    int uoff = l15 & 3;
#pragma unroll
    for (int ta = 0; ta < 4; ++ta)
#pragma unroll
        for (int v = 0; v < 4; ++v) {
            int li = wm + ta * 16 + q * 4 + v;
            u64 word = mwords[li * 4 + uoff];
            float rs = 0.f, ps = 0.f;
#pragma unroll
            for (int tb = 0; tb < 4; ++tb) {
                float s = __expf(2.f * d[ta][tb][v]);
                rs += s;
                ps += ((word >> (bitbase + tb * 4)) & 1ULL) ? s : 0.f;
            }
#pragma unroll
            for (int m = 1; m < 16; m <<= 1) {
                rs += __shfl_xor(rs, m, 16);
                ps += __shfl_xor(ps, m, 16);
            }
            if (l15 == 0) {
                atomicAdd(&rs_l[li], rs);
                atomicAdd(&ps_l[li], ps);
            }
        }
    __syncthreads();
    if (tid < 128) {
        atomicAdd(&rowsum[i0 + tid], rs_l[tid]);
        atomicAdd(&pos4[i0 + tid], ps_l[tid]);
    }
}

// ---------------- finalize ----------------

__global__ __launch_bounds__(256) void k_final(const float* __restrict__ rowsum,
                                               const float* __restrict__ pos2,
                                               const float* __restrict__ pos3,
                                               const float* __restrict__ pos4,
                                               const double* __restrict__ lacc,
                                               const double* __restrict__ pairsum,
                                               float* __restrict__ out) {
    __shared__ double red[4][4];
    int tid = threadIdx.x;
    double l2 = 0, l3 = 0, l4 = 0, sp = 0;
    for (int i = tid; i < N; i += 256) {
        double rs = (double)rowsum[i];
        float p2 = pos2[i], p3 = pos3[i], p4 = pos4[i];
        if (p2 > 0.f) l2 -= log((double)p2 / rs);
        if (p3 > 0.f) l3 -= log((double)p3 / rs);
        if (p4 > 0.f) l4 -= log((double)p4 / rs);
    }
    for (int i = tid; i < 1024; i += 256) sp += pairsum[i];
    int lane = tid & 63, wave = tid >> 6;
    for (int off = 32; off; off >>= 1) {
        l2 += __shfl_down(l2, off, 64);
        l3 += __shfl_down(l3, off, 64);
        l4 += __shfl_down(l4, off, 64);
        sp += __shfl_down(sp, off, 64);
    }
    if (lane == 0) { red[0][wave] = l2; red[1][wave] = l3; red[2][wave] = l4; red[3][wave] = sp; }
    __syncthreads();
    if (tid == 0) {
        double L2 = 0, L3 = 0, L4 = 0, SP = 0;
        for (int w = 0; w < 4; ++w) {
            L2 += red[0][w]; L3 += red[1][w]; L4 += red[2][w]; SP += red[3][w];
        }
        L2 /= N; L3 /= N; L4 /= N;
        double L1 = lacc[0] - 2.0 * lacc[2] + SP;   // sumA2 - 2*cross + sumP2
        double L5 = lacc[1];
        double total = L1 + 0.1 * (L2 + L3 + L4) + L5;
        out[0] = (float)total;
        out[1] = (float)L1;
        out[2] = (float)L2;
        out[3] = (float)L3;
        out[4] = (float)L4;
        out[5] = (float)L5;
    }
}

extern "C" void kernel_launch(void* const* d_in, const int* in_sizes, int n_in,
                              void* d_out, int out_size, void* d_ws, size_t ws_size,
                              hipStream_t stream) {
    const float* A     = (const float*)d_in[0];
    const float* U0    = (const float*)d_in[1];
    const float* U1    = (const float*)d_in[2];
    const float* U2    = (const float*)d_in[3];
    const float* V2    = (const float*)d_in[4];
    const float* fc1_w = (const float*)d_in[5];
    const float* fc1_b = (const float*)d_in[6];
    const float* fc2_w = (const float*)d_in[7];
    const float* fc2_b = (const float*)d_in[8];
    const float* sim   = (const float*)d_in[9];
    const int* cIdx    = (const int*)d_in[10];
    const int* nIdx    = (const int*)d_in[11];

    float* ws = (float*)d_ws;
    float* rowsum = ws;
    float* pos2 = ws + N;
    float* pos3 = ws + 2 * N;
    float* pos4 = ws + 3 * N;
    double* lacc = (double*)(ws + 4 * N);            // 4 doubles: sumA2, loss5, cross, (unused)
    double* pairsum = lacc + 4;                      // 1024 doubles
    u64* mask = (u64*)(pairsum + 1024);              // N*64 words = 2 MB
    bf16* hnb = (bf16*)(mask + (size_t)N * 64);      // 2 MB
    float* W  = (float*)(hnb + (size_t)N * S0);      // N*S2 fp32 = 1 MB
    float* Wt = W + (size_t)N * S2;                  // S2*N fp32 = 1 MB
    bf16* V2b = (bf16*)(Wt + (size_t)S2 * N);        // 0.5 MB

    k_prep<<<577, 128, 0, stream>>>(U0, U1, U2, V2, fc1_w, fc1_b, fc2_w, fc2_b,
                                    W, Wt, V2b, hnb, ws);
    k_mid<<<2344, 256, 0, stream>>>(sim, mask, U0, U1, U2, V2, A, V2b, W, Wt,
                                    lacc, pairsum);
    k_sim<<<1024 + 384, 256, 0, stream>>>(hnb, mask, rowsum, pos4,
                                          cIdx, nIdx, pos2, pos3);
    k_final<<<1, 256, 0, stream>>>(rowsum, pos2, pos3, pos4, lacc, pairsum,
                                   (float*)d_out);
}